// Round 5
// baseline (329.876 us; speedup 1.0000x reference)
//
#include <hip/hip_runtime.h>
#include <hip/hip_bf16.h>
#include <stdint.h>

typedef __bf16 bf16;
typedef __attribute__((ext_vector_type(4))) float f32x4;
typedef __attribute__((ext_vector_type(8))) bf16 bf16x8;
typedef __attribute__((ext_vector_type(4))) bf16 bf16x4;

#define AS1 __attribute__((address_space(1)))
#define AS3 __attribute__((address_space(3)))

static __device__ __forceinline__ void gload_lds16(const bf16* g, bf16* l) {
  __builtin_amdgcn_global_load_lds((const AS1 void*)g, (AS3 void*)l, 16, 0, 0);
}

#define BAR __builtin_amdgcn_s_barrier()
#define LGKM0 asm volatile("s_waitcnt lgkmcnt(0)" ::: "memory")
#define VMC0 asm volatile("s_waitcnt vmcnt(0)" ::: "memory")
#define SCHED0 __builtin_amdgcn_sched_barrier(0)

// Stage one 128x64 bf16 tile (16 KB) with 256 threads (4 chunks each).
// LDS dest linear; global source chunk-XOR pre-swizzled (c ^= row&7).
#define STAGE_T(gsrc, dst, kt_) do {                                          \
  _Pragma("unroll") for (int s_ = 0; s_ < 4; ++s_) {                          \
    int idx_ = s_ * 256 + tid;                                                \
    int r_ = idx_ >> 3, c_ = idx_ & 7;                                        \
    gload_lds16((gsrc) + (size_t)r_ * 512 + ((kt_) << 6) + ((c_ ^ (r_ & 7)) << 3), \
                (dst) + idx_ * 8);                                            \
  }                                                                           \
} while (0)

// 2-phase K-loop: BM=BN=128, BK=64, 8 K-tiles, 4 waves (2Mx2N).
// One vmcnt(0)+barrier per kt (publish), reads always after the barrier
// that published their buffer.
#define KLOOP_128(Ag, Bg)                                                     \
  f32x4 acc[4][4] = {};                                                       \
  STAGE_T(Ag, SA0, 0); STAGE_T(Bg, SB0, 0);                                   \
  VMC0; BAR;                                                                  \
  _Pragma("unroll 2")                                                         \
  for (int kt = 0; kt < 8; ++kt) {                                            \
    bf16* Ap = (kt & 1) ? SA1 : SA0;                                          \
    bf16* An = (kt & 1) ? SA0 : SA1;                                          \
    bf16* Bp = (kt & 1) ? SB1 : SB0;                                          \
    bf16* Bn = (kt & 1) ? SB0 : SB1;                                          \
    if (kt < 7) { STAGE_T(Ag, An, kt + 1); STAGE_T(Bg, Bn, kt + 1); }         \
    bf16x8 af[4][2], bfr[4][2];                                               \
    _Pragma("unroll") for (int i_ = 0; i_ < 4; ++i_) {                        \
      int ra_ = wr + i_ * 16 + lr, rb_ = wc + i_ * 16 + lr;                   \
      _Pragma("unroll") for (int ks_ = 0; ks_ < 2; ++ks_) {                   \
        af[i_][ks_]  = *(const bf16x8*)(Ap + ra_ * 64 + (((ks_ * 4 + lg) ^ (ra_ & 7)) << 3)); \
        bfr[i_][ks_] = *(const bf16x8*)(Bp + rb_ * 64 + (((ks_ * 4 + lg) ^ (rb_ & 7)) << 3)); \
      }                                                                       \
    }                                                                         \
    LGKM0; SCHED0;                                                            \
    __builtin_amdgcn_s_setprio(1);                                            \
    _Pragma("unroll") for (int i_ = 0; i_ < 4; ++i_)                          \
    _Pragma("unroll") for (int j_ = 0; j_ < 4; ++j_)                          \
    _Pragma("unroll") for (int ks_ = 0; ks_ < 2; ++ks_)                       \
      acc[i_][j_] = __builtin_amdgcn_mfma_f32_16x16x32_bf16(                  \
          af[i_][ks_], bfr[j_][ks_], acc[i_][j_], 0, 0, 0);                   \
    __builtin_amdgcn_s_setprio(0);                                            \
    if (kt < 7) VMC0;                                                         \
    BAR;                                                                      \
  }

// ---------------- prep: roll + reorder + fp32->bf16 ----------------
__global__ __launch_bounds__(256) void prep_x(const float* __restrict__ x,
                                              bf16* __restrict__ xs) {
  int m = blockIdx.x * 8 + (threadIdx.x >> 5);
  int lane = threadIdx.x & 31;
  int b = m >> 12, win = (m >> 6) & 63, t = m & 63;
  int ip = ((win >> 3) << 3) + (t >> 3);
  int jp = ((win & 7) << 3) + (t & 7);
  int io = (ip + 4) & 63, jo = (jp + 4) & 63;
  const float* src = x + ((((size_t)(b << 6) + io) << 6) + jo) * 512;
  bf16* dst = xs + ((size_t)m << 9);
  #pragma unroll
  for (int c0 = 0; c0 < 512; c0 += 128) {
    int c = c0 + lane * 4;
    float4 v = *(const float4*)(src + c);
    bf16x4 o = { (bf16)v.x, (bf16)v.y, (bf16)v.z, (bf16)v.w };
    *(bf16x4*)(dst + c) = o;
  }
}

__global__ __launch_bounds__(256) void prep_w(const float* __restrict__ wqkv,
                                              const float* __restrict__ wout,
                                              bf16* __restrict__ wqkv_bf,
                                              bf16* __restrict__ wout_bf) {
  int r = blockIdx.x * 8 + (threadIdx.x >> 5);
  int lane = threadIdx.x & 31;
  const float* src;
  bf16* dst;
  float sc = 1.0f;
  if (r < 1536) {
    src = wqkv + (size_t)r * 512;
    dst = wqkv_bf + (size_t)r * 512;
    if (r < 512) sc = 0.17677669529663689f;
  } else {
    int r2 = r - 1536;
    src = wout + (size_t)r2 * 512;
    dst = wout_bf + (size_t)r2 * 512;
  }
  #pragma unroll
  for (int c0 = 0; c0 < 512; c0 += 128) {
    int c = c0 + lane * 4;
    float4 v = *(const float4*)(src + c);
    bf16x4 o = { (bf16)(v.x * sc), (bf16)(v.y * sc), (bf16)(v.z * sc), (bf16)(v.w * sc) };
    *(bf16x4*)(dst + c) = o;
  }
}

__global__ __launch_bounds__(256) void prep_bias(const float* __restrict__ pos,
                                                 float* __restrict__ bias4) {
  for (int idx = threadIdx.x; idx < 4 * 4096; idx += 256) {
    int ty = idx >> 12, ij = idx & 4095;
    int i = ij >> 6, j = ij & 63;
    int rx = ((j >> 3) - (i >> 3)) + 7;
    int ry = ((j & 7) - (i & 7)) + 7;
    float v = pos[rx * 15 + ry];
    if ((ty & 1) && (((i ^ j) >> 5) & 1)) v = -1e30f;
    if ((ty & 2) && (((i ^ j) >> 2) & 1)) v = -1e30f;
    bias4[idx] = v;
  }
}

// ---------------- QKV GEMM: 128x128, BK=64, 2-phase ----------------
__global__ __launch_bounds__(256, 2) void gemm_qkv(
    const bf16* __restrict__ xs, const bf16* __restrict__ wb,
    bf16* __restrict__ qb, bf16* __restrict__ kb, bf16* __restrict__ vb) {
  __shared__ union {
    struct { bf16 A[2][8192]; bf16 B[2][8192]; } s;
    bf16 C[128][128];
  } sm;
  bf16* SA0 = sm.s.A[0]; bf16* SA1 = sm.s.A[1];
  bf16* SB0 = sm.s.B[0]; bf16* SB1 = sm.s.B[1];

  const int tid = threadIdx.x, wave = tid >> 6, lane = tid & 63;
  int bid = blockIdx.x;
  bid = (bid & 7) * 768 + (bid >> 3);          // XCD swizzle (6144 = 8*768)
  const int mt = bid / 12, nt = bid % 12;

  const bf16* Ag = xs + ((size_t)mt * 128) * 512;
  const bf16* Bg = wb + ((size_t)nt * 128) * 512;

  const int wr = (wave >> 1) << 6, wc = (wave & 1) << 6;
  const int lr = lane & 15, lg = lane >> 4;

  KLOOP_128(Ag, Bg)

  // acc -> swizzled bf16 C tile in LDS (loop's final BAR synced everyone)
  #pragma unroll
  for (int i = 0; i < 4; ++i)
    #pragma unroll
    for (int j = 0; j < 4; ++j)
      #pragma unroll
      for (int r = 0; r < 4; ++r) {
        int row = wr + i * 16 + (lg << 2) + r;
        int col = wc + j * 16 + lr;
        sm.C[row][col ^ ((row & 7) << 3)] = (bf16)acc[i][j][r];
      }
  __syncthreads();
  const int sel = nt >> 2;                     // 0=q, 1=k, 2=v
  #pragma unroll
  for (int ch = 0; ch < 2; ++ch) {
    int c = wave * 2 + ch;
    int wl = c >> 2, hl = c & 3;               // window-in-tile, head-in-tile
    int gw = mt * 2 + wl;
    int b = gw >> 6, win = gw & 63;
    int h = ((nt & 3) << 2) + hl;
    size_t ubase = ((size_t)((b << 4) + h) * 64 + win) * 2048;
    if (sel < 2) {
      bf16* dst = (sel == 0 ? qb : kb) + ubase;
      #pragma unroll
      for (int p = 0; p < 4; ++p) {
        int off = p * 512 + lane * 8;
        int t = off >> 5, d = off & 31;
        int row = (wl << 6) + t, col = (hl << 5) + d;
        bf16x8 v = *(const bf16x8*)&sm.C[row][col ^ ((row & 7) << 3)];
        *(bf16x8*)(dst + off) = v;             // q/k: [t][d]
      }
    } else {
      bf16* dst = vb + ubase;
      #pragma unroll
      for (int p = 0; p < 4; ++p) {
        int off = p * 512 + lane * 8;
        int d = off >> 6, t0 = off & 63;
        int col = (hl << 5) + d;
        bf16x8 v;
        #pragma unroll
        for (int q = 0; q < 8; ++q) {
          int row = (wl << 6) + t0 + q;
          v[q] = sm.C[row][col ^ ((row & 7) << 3)];
        }
        *(bf16x8*)(dst + off) = v;             // v: [d][t] (transposed)
      }
    }
  }
}

// ---------------- window attention: 1 wave per (b,h,win) ----------------
__global__ __launch_bounds__(256) void attn(
    const bf16* __restrict__ qb, const bf16* __restrict__ kb,
    const bf16* __restrict__ vb, const float* __restrict__ bias4,
    bf16* __restrict__ ao) {
  __shared__ bf16 Ps[4][64][72];
  const int wave = threadIdx.x >> 6, lane = threadIdx.x & 63;
  const int u = blockIdx.x * 4 + wave;
  const int b = u >> 10, h = (u >> 6) & 15, win = u & 63;
  const int lr = lane & 15, lg = lane >> 4;

  const bf16* qu = qb + (size_t)u * 2048;
  const bf16* ku = kb + (size_t)u * 2048;
  const bf16* vu = vb + (size_t)u * 2048;

  bf16x8 qf[4], kf[4];
  #pragma unroll
  for (int i = 0; i < 4; ++i) {
    qf[i] = *(const bf16x8*)(qu + (i * 16 + lr) * 32 + (lg << 3));
    kf[i] = *(const bf16x8*)(ku + (i * 16 + lr) * 32 + (lg << 3));
  }
  f32x4 s[4][4] = {};
  #pragma unroll
  for (int i = 0; i < 4; ++i)
    #pragma unroll
    for (int j = 0; j < 4; ++j)
      s[i][j] = __builtin_amdgcn_mfma_f32_16x16x32_bf16(qf[i], kf[j], s[i][j], 0, 0, 0);

  const int ty = ((win >= 56) ? 1 : 0) | (((win & 7) == 7) ? 2 : 0);
  const float* bt = bias4 + ty * 4096;
  #pragma unroll
  for (int i = 0; i < 4; ++i)
    #pragma unroll
    for (int r = 0; r < 4; ++r) {
      int row = i * 16 + (lg << 2) + r;
      #pragma unroll
      for (int j = 0; j < 4; ++j)
        s[i][j][r] += bt[row * 64 + j * 16 + lr];
    }
  #pragma unroll
  for (int i = 0; i < 4; ++i)
    #pragma unroll
    for (int r = 0; r < 4; ++r) {
      float mx = fmaxf(fmaxf(s[i][0][r], s[i][1][r]), fmaxf(s[i][2][r], s[i][3][r]));
      mx = fmaxf(mx, __shfl_xor(mx, 1));
      mx = fmaxf(mx, __shfl_xor(mx, 2));
      mx = fmaxf(mx, __shfl_xor(mx, 4));
      mx = fmaxf(mx, __shfl_xor(mx, 8));
      float sum = 0.f;
      #pragma unroll
      for (int j = 0; j < 4; ++j) { s[i][j][r] = __expf(s[i][j][r] - mx); sum += s[i][j][r]; }
      sum += __shfl_xor(sum, 1);
      sum += __shfl_xor(sum, 2);
      sum += __shfl_xor(sum, 4);
      sum += __shfl_xor(sum, 8);
      float inv = 1.0f / sum;
      int row = i * 16 + (lg << 2) + r;
      #pragma unroll
      for (int j = 0; j < 4; ++j)
        Ps[wave][row][j * 16 + lr] = (bf16)(s[i][j][r] * inv);
    }
  f32x4 o[4][2] = {};
  #pragma unroll
  for (int kk = 0; kk < 2; ++kk) {
    bf16x8 vf[2];
    #pragma unroll
    for (int nj = 0; nj < 2; ++nj)
      vf[nj] = *(const bf16x8*)(vu + (nj * 16 + lr) * 64 + kk * 32 + (lg << 3));
    #pragma unroll
    for (int mi = 0; mi < 4; ++mi) {
      bf16x8 pa = *(const bf16x8*)&Ps[wave][mi * 16 + lr][kk * 32 + (lg << 3)];
      #pragma unroll
      for (int nj = 0; nj < 2; ++nj)
        o[mi][nj] = __builtin_amdgcn_mfma_f32_16x16x32_bf16(pa, vf[nj], o[mi][nj], 0, 0, 0);
    }
  }
  bf16* dst = ao + ((size_t)(b * 64 + win) * 64) * 512 + h * 32;
  #pragma unroll
  for (int mi = 0; mi < 4; ++mi)
    #pragma unroll
    for (int r = 0; r < 4; ++r) {
      int t = mi * 16 + (lg << 2) + r;
      #pragma unroll
      for (int nj = 0; nj < 2; ++nj)
        dst[(size_t)t * 512 + nj * 16 + lr] = (bf16)o[mi][nj][r];
    }
}

// ---------------- out-proj GEMM (128x128, BK=64) + bias + inverse roll ----------------
__global__ __launch_bounds__(256, 2) void gemm_out(
    const bf16* __restrict__ ao, const bf16* __restrict__ wob,
    const float* __restrict__ bout, float* __restrict__ out) {
  __shared__ struct { bf16 A[2][8192]; bf16 B[2][8192]; } smo;
  bf16* SA0 = smo.A[0]; bf16* SA1 = smo.A[1];
  bf16* SB0 = smo.B[0]; bf16* SB1 = smo.B[1];

  const int tid = threadIdx.x, wave = tid >> 6, lane = tid & 63;
  int bid = blockIdx.x;
  bid = (bid & 7) * 256 + (bid >> 3);          // XCD swizzle (2048 = 8*256)
  const int mt = bid >> 2, nt = bid & 3;
  const bf16* Ag = ao + ((size_t)mt * 128) * 512;
  const bf16* Bg = wob + ((size_t)nt * 128) * 512;

  const int wr = (wave >> 1) << 6, wc = (wave & 1) << 6;
  const int lr = lane & 15, lg = lane >> 4;

  KLOOP_128(Ag, Bg)

  float bv[4];
  #pragma unroll
  for (int j = 0; j < 4; ++j) bv[j] = bout[nt * 128 + wc + j * 16 + lr];
  #pragma unroll
  for (int i = 0; i < 4; ++i)
    #pragma unroll
    for (int r = 0; r < 4; ++r) {
      int m = (mt << 7) + wr + i * 16 + (lg << 2) + r;
      int b = m >> 12, win = (m >> 6) & 63, t = m & 63;
      int ip = ((win >> 3) << 3) + (t >> 3);
      int jp = ((win & 7) << 3) + (t & 7);
      int io = (ip + 4) & 63, jo = (jp + 4) & 63;
      float* orow = out + ((((size_t)(b << 6) + io) << 6) + jo) * 512 + nt * 128 + wc;
      #pragma unroll
      for (int j = 0; j < 4; ++j)
        orow[j * 16 + lr] = acc[i][j][r] + bv[j];
    }
}

extern "C" void kernel_launch(void* const* d_in, const int* in_sizes, int n_in,
                              void* d_out, int out_size, void* d_ws, size_t ws_size,
                              hipStream_t stream) {
  const float* x    = (const float*)d_in[0];
  const float* wqkv = (const float*)d_in[1];
  const float* pos  = (const float*)d_in[2];
  const float* wout = (const float*)d_in[3];
  const float* bout = (const float*)d_in[4];
  float* out = (float*)d_out;

  char* ws = (char*)d_ws;
  bf16* xs      = (bf16*)(ws);
  bf16* qb      = (bf16*)(ws + 67108864);
  bf16* kb      = (bf16*)(ws + 134217728);
  bf16* vb      = (bf16*)(ws + 201326592);
  bf16* wqkv_bf = (bf16*)(ws + 268435456);
  bf16* wout_bf = (bf16*)(ws + 270008320);
  float* bias4  = (float*)(ws + 270532608);

  prep_x<<<dim3(8192), dim3(256), 0, stream>>>(x, xs);
  prep_w<<<dim3(256), dim3(256), 0, stream>>>(wqkv, wout, wqkv_bf, wout_bf);
  prep_bias<<<dim3(1), dim3(256), 0, stream>>>(pos, bias4);
  gemm_qkv<<<dim3(6144), dim3(256), 0, stream>>>(xs, wqkv_bf, qb, kb, vb);
  attn<<<dim3(4096), dim3(256), 0, stream>>>(qb, kb, vb, bias4, xs);
  gemm_out<<<dim3(2048), dim3(256), 0, stream>>>(xs, wout_bf, bout, out);
}

// Round 6
// 307.849 us; speedup vs baseline: 1.0716x; 1.0716x over previous
//
#include <hip/hip_runtime.h>
#include <hip/hip_bf16.h>
#include <stdint.h>

typedef __bf16 bf16;
typedef __attribute__((ext_vector_type(4))) float f32x4;
typedef __attribute__((ext_vector_type(8))) bf16 bf16x8;
typedef __attribute__((ext_vector_type(4))) bf16 bf16x4;

#define AS1 __attribute__((address_space(1)))
#define AS3 __attribute__((address_space(3)))

static __device__ __forceinline__ void gload_lds16(const bf16* g, bf16* l) {
  __builtin_amdgcn_global_load_lds((const AS1 void*)g, (AS3 void*)l, 16, 0, 0);
}

#define BAR __builtin_amdgcn_s_barrier()
#define LGKM0 asm volatile("s_waitcnt lgkmcnt(0)" ::: "memory")
#define VMC(n) asm volatile("s_waitcnt vmcnt(" #n ")" ::: "memory")
#define SCHED0 __builtin_amdgcn_sched_barrier(0)

// Stage one 128x64 bf16 A-tile (16 KB): 256 threads x 4 gload_lds16.
// LDS dest linear; global source chunk-XOR pre-swizzled (c ^= row&7).
#define STAGE_A(gsrc, dst, kt_) do {                                          \
  _Pragma("unroll") for (int s_ = 0; s_ < 4; ++s_) {                          \
    int idx_ = s_ * 256 + tid;                                                \
    int r_ = idx_ >> 3, c_ = idx_ & 7;                                        \
    gload_lds16((gsrc) + (size_t)r_ * 512 + ((kt_) << 6) + ((c_ ^ (r_ & 7)) << 3), \
                (dst) + idx_ * 8);                                            \
  }                                                                           \
} while (0)

// B fragments straight from global (K-major layout bt[k/8][col][8], L2-resident):
// bfr[cb][ks] = B^T[colbase+wc+cb*16+lr][kt*64 + ks*32 + lg*8 .. +8]
#define LOADB(ktq, NCOLX) do {                                                \
  const bf16* bp_ = Bptr + (size_t)(ktq) * ((size_t)(NCOLX) * 64);            \
  _Pragma("unroll") for (int cb_ = 0; cb_ < 4; ++cb_)                         \
  _Pragma("unroll") for (int ks_ = 0; ks_ < 2; ++ks_)                         \
    bfr[cb_][ks_] = *(const bf16x8*)(bp_ + cb_ * 128 + (size_t)ks_ * (NCOLX) * 32); \
} while (0)

// K-loop: BM=BN=128, BK=64, 8 K-tiles, 4 waves (2Mx2N, 64x64/wave).
// A double-buffered in LDS (one barrier + one counted publish per kt);
// B single-buffered in regs, prefetched one kt ahead (per-wave, no barrier).
// Invariant entering kt: in-flight = Bf(kt)[8] then Ast(kt+1)[4].
#define KLOOP_BD(Ag, NCOLX)                                                   \
  f32x4 acc[4][4] = {};                                                       \
  bf16x8 af[4][2], bfr[4][2];                                                 \
  STAGE_A(Ag, SA0, 0);                                                        \
  LOADB(0, NCOLX);                                                            \
  VMC(8); BAR;                /* drain Ast(0), publish A(0); Bf(0) in flight */ \
  STAGE_A(Ag, SA1, 1);                                                        \
  _Pragma("unroll 2")                                                         \
  for (int kt = 0; kt < 8; ++kt) {                                            \
    bf16* Ap = (kt & 1) ? SA1 : SA0;                                          \
    _Pragma("unroll") for (int i_ = 0; i_ < 4; ++i_) {                        \
      int ra_ = wr + i_ * 16 + lr;                                            \
      _Pragma("unroll") for (int ks_ = 0; ks_ < 2; ++ks_)                     \
        af[i_][ks_] = *(const bf16x8*)(Ap + ra_ * 64 + (((ks_ * 4 + lg) ^ (ra_ & 7)) << 3)); \
    }                                                                         \
    LGKM0; SCHED0;            /* af ready; compiler auto-vmcnt covers bfr */  \
    __builtin_amdgcn_s_setprio(1);                                            \
    _Pragma("unroll") for (int i_ = 0; i_ < 4; ++i_)                          \
    _Pragma("unroll") for (int j_ = 0; j_ < 4; ++j_)                          \
    _Pragma("unroll") for (int ks_ = 0; ks_ < 2; ++ks_)                       \
      acc[i_][j_] = __builtin_amdgcn_mfma_f32_16x16x32_bf16(                  \
          af[i_][ks_], bfr[j_][ks_], acc[i_][j_], 0, 0, 0);                   \
    __builtin_amdgcn_s_setprio(0);                                            \
    if (kt < 7) LOADB(kt + 1, NCOLX);   /* WAR on bfr keeps this after MFMA */ \
    if (kt < 7) { VMC(8); }   /* drain Ast(kt+1); leave Bf(kt+1)[8] */        \
    BAR;                      /* publish A(kt+1); all waves done with A(kt) */ \
    if (kt < 6) STAGE_A(Ag, Ap, kt + 2);  /* refill freed slot -> invariant */ \
  }

// ---------------- prep: roll + reorder + fp32->bf16 ----------------
__global__ __launch_bounds__(256) void prep_x(const float* __restrict__ x,
                                              bf16* __restrict__ xs) {
  int m = blockIdx.x * 8 + (threadIdx.x >> 5);
  int lane = threadIdx.x & 31;
  int b = m >> 12, win = (m >> 6) & 63, t = m & 63;
  int ip = ((win >> 3) << 3) + (t >> 3);
  int jp = ((win & 7) << 3) + (t & 7);
  int io = (ip + 4) & 63, jo = (jp + 4) & 63;
  const float* src = x + ((((size_t)(b << 6) + io) << 6) + jo) * 512;
  bf16* dst = xs + ((size_t)m << 9);
  #pragma unroll
  for (int c0 = 0; c0 < 512; c0 += 128) {
    int c = c0 + lane * 4;
    float4 v = *(const float4*)(src + c);
    bf16x4 o = { (bf16)v.x, (bf16)v.y, (bf16)v.z, (bf16)v.w };
    *(bf16x4*)(dst + c) = o;
  }
}

// Weights -> bf16, K-major-grouped: bt[kblk=k/8][col][8]. q-scale folded.
__global__ __launch_bounds__(256) void prep_w(const float* __restrict__ wqkv,
                                              const float* __restrict__ wout,
                                              bf16* __restrict__ wqkv_bt,
                                              bf16* __restrict__ wout_bt) {
  int r = blockIdx.x * 8 + (threadIdx.x >> 5);
  int lane = threadIdx.x & 31;
  const float* src;
  bf16* dstb;
  int ncol, col;
  float sc = 1.0f;
  if (r < 1536) {
    src = wqkv + (size_t)r * 512; dstb = wqkv_bt; ncol = 1536; col = r;
    if (r < 512) sc = 0.17677669529663689f;
  } else {
    src = wout + (size_t)(r - 1536) * 512; dstb = wout_bt; ncol = 512; col = r - 1536;
  }
  #pragma unroll
  for (int kb = lane; kb < 64; kb += 32) {
    float4 v0 = *(const float4*)(src + kb * 8);
    float4 v1 = *(const float4*)(src + kb * 8 + 4);
    bf16x8 o = { (bf16)(v0.x * sc), (bf16)(v0.y * sc), (bf16)(v0.z * sc), (bf16)(v0.w * sc),
                 (bf16)(v1.x * sc), (bf16)(v1.y * sc), (bf16)(v1.z * sc), (bf16)(v1.w * sc) };
    *(bf16x8*)(dstb + ((size_t)kb * ncol + col) * 8) = o;
  }
}

__global__ __launch_bounds__(256) void prep_bias(const float* __restrict__ pos,
                                                 float* __restrict__ bias4) {
  for (int idx = threadIdx.x; idx < 4 * 4096; idx += 256) {
    int ty = idx >> 12, ij = idx & 4095;
    int i = ij >> 6, j = ij & 63;
    int rx = ((j >> 3) - (i >> 3)) + 7;
    int ry = ((j & 7) - (i & 7)) + 7;
    float v = pos[rx * 15 + ry];
    if ((ty & 1) && (((i ^ j) >> 5) & 1)) v = -1e30f;
    if ((ty & 2) && (((i ^ j) >> 2) & 1)) v = -1e30f;
    bias4[idx] = v;
  }
}

// ---------------- QKV GEMM: 128x128, BK=64, A-in-LDS / B-from-L2 ----------------
__global__ __launch_bounds__(256, 3) void gemm_qkv(
    const bf16* __restrict__ xs, const bf16* __restrict__ wb,
    bf16* __restrict__ qb, bf16* __restrict__ kb, bf16* __restrict__ vb) {
  __shared__ union { bf16 A[2][8192]; bf16 C[128][128]; } sm;
  bf16* SA0 = sm.A[0]; bf16* SA1 = sm.A[1];

  const int tid = threadIdx.x, wave = tid >> 6, lane = tid & 63;
  int bid = blockIdx.x;
  bid = (bid & 7) * 768 + (bid >> 3);          // XCD swizzle (6144 = 8*768)
  const int mt = bid / 12, nt = bid % 12;

  const bf16* Ag = xs + ((size_t)mt * 128) * 512;
  const int wr = (wave >> 1) << 6, wc = (wave & 1) << 6;
  const int lr = lane & 15, lg = lane >> 4;
  const bf16* Bptr = wb + (((size_t)lg * 1536) + nt * 128 + wc + lr) * 8;

  KLOOP_BD(Ag, 1536)

  // acc -> swizzled bf16 C tile in LDS (loop's final BAR synced everyone)
  #pragma unroll
  for (int i = 0; i < 4; ++i)
    #pragma unroll
    for (int j = 0; j < 4; ++j)
      #pragma unroll
      for (int r = 0; r < 4; ++r) {
        int row = wr + i * 16 + (lg << 2) + r;
        int col = wc + j * 16 + lr;
        sm.C[row][col ^ ((row & 7) << 3)] = (bf16)acc[i][j][r];
      }
  __syncthreads();
  const int sel = nt >> 2;                     // 0=q, 1=k, 2=v
  #pragma unroll
  for (int ch = 0; ch < 2; ++ch) {
    int c = wave * 2 + ch;
    int wl = c >> 2, hl = c & 3;               // window-in-tile, head-in-tile
    int gw = mt * 2 + wl;
    int b = gw >> 6, win = gw & 63;
    int h = ((nt & 3) << 2) + hl;
    size_t ubase = ((size_t)((b << 4) + h) * 64 + win) * 2048;
    if (sel < 2) {
      bf16* dst = (sel == 0 ? qb : kb) + ubase;
      #pragma unroll
      for (int p = 0; p < 4; ++p) {
        int off = p * 512 + lane * 8;
        int t = off >> 5, d = off & 31;
        int row = (wl << 6) + t, col = (hl << 5) + d;
        bf16x8 v = *(const bf16x8*)&sm.C[row][col ^ ((row & 7) << 3)];
        *(bf16x8*)(dst + off) = v;             // q/k: [t][d]
      }
    } else {
      bf16* dst = vb + ubase;
      #pragma unroll
      for (int p = 0; p < 4; ++p) {
        int off = p * 512 + lane * 8;
        int d = off >> 6, t0 = off & 63;
        int col = (hl << 5) + d;
        bf16x8 v;
        #pragma unroll
        for (int q = 0; q < 8; ++q) {
          int row = (wl << 6) + t0 + q;
          v[q] = sm.C[row][col ^ ((row & 7) << 3)];
        }
        *(bf16x8*)(dst + off) = v;             // v: [d][t] (transposed)
      }
    }
  }
}

// ---------------- window attention: 1 wave per (b,h,win) ----------------
__global__ __launch_bounds__(256) void attn(
    const bf16* __restrict__ qb, const bf16* __restrict__ kb,
    const bf16* __restrict__ vb, const float* __restrict__ bias4,
    bf16* __restrict__ ao) {
  __shared__ bf16 Ps[4][64][72];
  const int wave = threadIdx.x >> 6, lane = threadIdx.x & 63;
  const int u = blockIdx.x * 4 + wave;
  const int b = u >> 10, h = (u >> 6) & 15, win = u & 63;
  const int lr = lane & 15, lg = lane >> 4;

  const bf16* qu = qb + (size_t)u * 2048;
  const bf16* ku = kb + (size_t)u * 2048;
  const bf16* vu = vb + (size_t)u * 2048;

  bf16x8 qf[4], kf[4];
  #pragma unroll
  for (int i = 0; i < 4; ++i) {
    qf[i] = *(const bf16x8*)(qu + (i * 16 + lr) * 32 + (lg << 3));
    kf[i] = *(const bf16x8*)(ku + (i * 16 + lr) * 32 + (lg << 3));
  }
  f32x4 s[4][4] = {};
  #pragma unroll
  for (int i = 0; i < 4; ++i)
    #pragma unroll
    for (int j = 0; j < 4; ++j)
      s[i][j] = __builtin_amdgcn_mfma_f32_16x16x32_bf16(qf[i], kf[j], s[i][j], 0, 0, 0);

  const int ty = ((win >= 56) ? 1 : 0) | (((win & 7) == 7) ? 2 : 0);
  const float* bt = bias4 + ty * 4096;
  #pragma unroll
  for (int i = 0; i < 4; ++i)
    #pragma unroll
    for (int r = 0; r < 4; ++r) {
      int row = i * 16 + (lg << 2) + r;
      #pragma unroll
      for (int j = 0; j < 4; ++j)
        s[i][j][r] += bt[row * 64 + j * 16 + lr];
    }
  #pragma unroll
  for (int i = 0; i < 4; ++i)
    #pragma unroll
    for (int r = 0; r < 4; ++r) {
      float mx = fmaxf(fmaxf(s[i][0][r], s[i][1][r]), fmaxf(s[i][2][r], s[i][3][r]));
      mx = fmaxf(mx, __shfl_xor(mx, 1));
      mx = fmaxf(mx, __shfl_xor(mx, 2));
      mx = fmaxf(mx, __shfl_xor(mx, 4));
      mx = fmaxf(mx, __shfl_xor(mx, 8));
      float sum = 0.f;
      #pragma unroll
      for (int j = 0; j < 4; ++j) { s[i][j][r] = __expf(s[i][j][r] - mx); sum += s[i][j][r]; }
      sum += __shfl_xor(sum, 1);
      sum += __shfl_xor(sum, 2);
      sum += __shfl_xor(sum, 4);
      sum += __shfl_xor(sum, 8);
      float inv = 1.0f / sum;
      int row = i * 16 + (lg << 2) + r;
      #pragma unroll
      for (int j = 0; j < 4; ++j)
        Ps[wave][row][j * 16 + lr] = (bf16)(s[i][j][r] * inv);
    }
  f32x4 o[4][2] = {};
  #pragma unroll
  for (int kk = 0; kk < 2; ++kk) {
    bf16x8 vf[2];
    #pragma unroll
    for (int nj = 0; nj < 2; ++nj)
      vf[nj] = *(const bf16x8*)(vu + (nj * 16 + lr) * 64 + kk * 32 + (lg << 3));
    #pragma unroll
    for (int mi = 0; mi < 4; ++mi) {
      bf16x8 pa = *(const bf16x8*)&Ps[wave][mi * 16 + lr][kk * 32 + (lg << 3)];
      #pragma unroll
      for (int nj = 0; nj < 2; ++nj)
        o[mi][nj] = __builtin_amdgcn_mfma_f32_16x16x32_bf16(pa, vf[nj], o[mi][nj], 0, 0, 0);
    }
  }
  bf16* dst = ao + ((size_t)(b * 64 + win) * 64) * 512 + h * 32;
  #pragma unroll
  for (int mi = 0; mi < 4; ++mi)
    #pragma unroll
    for (int r = 0; r < 4; ++r) {
      int t = mi * 16 + (lg << 2) + r;
      #pragma unroll
      for (int nj = 0; nj < 2; ++nj)
        dst[(size_t)t * 512 + nj * 16 + lr] = (bf16)o[mi][nj][r];
    }
}

// ---------------- out-proj GEMM + bias + inverse roll ----------------
__global__ __launch_bounds__(256, 3) void gemm_out(
    const bf16* __restrict__ ao, const bf16* __restrict__ wob,
    const float* __restrict__ bout, float* __restrict__ out) {
  __shared__ bf16 SA[2][8192];
  bf16* SA0 = SA[0]; bf16* SA1 = SA[1];

  const int tid = threadIdx.x, wave = tid >> 6, lane = tid & 63;
  int bid = blockIdx.x;
  bid = (bid & 7) * 256 + (bid >> 3);          // XCD swizzle (2048 = 8*256)
  const int mt = bid >> 2, nt = bid & 3;
  const bf16* Ag = ao + ((size_t)mt * 128) * 512;
  const int wr = (wave >> 1) << 6, wc = (wave & 1) << 6;
  const int lr = lane & 15, lg = lane >> 4;
  const bf16* Bptr = wob + (((size_t)lg * 512) + nt * 128 + wc + lr) * 8;

  KLOOP_BD(Ag, 512)

  float bv[4];
  #pragma unroll
  for (int j = 0; j < 4; ++j) bv[j] = bout[nt * 128 + wc + j * 16 + lr];
  #pragma unroll
  for (int i = 0; i < 4; ++i)
    #pragma unroll
    for (int r = 0; r < 4; ++r) {
      int m = (mt << 7) + wr + i * 16 + (lg << 2) + r;
      int b = m >> 12, win = (m >> 6) & 63, t = m & 63;
      int ip = ((win >> 3) << 3) + (t >> 3);
      int jp = ((win & 7) << 3) + (t & 7);
      int io = (ip + 4) & 63, jo = (jp + 4) & 63;
      float* orow = out + ((((size_t)(b << 6) + io) << 6) + jo) * 512 + nt * 128 + wc;
      #pragma unroll
      for (int j = 0; j < 4; ++j)
        orow[j * 16 + lr] = acc[i][j][r] + bv[j];
    }
}

extern "C" void kernel_launch(void* const* d_in, const int* in_sizes, int n_in,
                              void* d_out, int out_size, void* d_ws, size_t ws_size,
                              hipStream_t stream) {
  const float* x    = (const float*)d_in[0];
  const float* wqkv = (const float*)d_in[1];
  const float* pos  = (const float*)d_in[2];
  const float* wout = (const float*)d_in[3];
  const float* bout = (const float*)d_in[4];
  float* out = (float*)d_out;

  char* ws = (char*)d_ws;
  bf16* xs      = (bf16*)(ws);
  bf16* qb      = (bf16*)(ws + 67108864);
  bf16* kb      = (bf16*)(ws + 134217728);
  bf16* vb      = (bf16*)(ws + 201326592);
  bf16* wqkv_bf = (bf16*)(ws + 268435456);
  bf16* wout_bf = (bf16*)(ws + 270008320);
  float* bias4  = (float*)(ws + 270532608);

  prep_x<<<dim3(8192), dim3(256), 0, stream>>>(x, xs);
  prep_w<<<dim3(256), dim3(256), 0, stream>>>(wqkv, wout, wqkv_bf, wout_bf);
  prep_bias<<<dim3(1), dim3(256), 0, stream>>>(pos, bias4);
  gemm_qkv<<<dim3(6144), dim3(256), 0, stream>>>(xs, wqkv_bf, qb, kb, vb);
  attn<<<dim3(4096), dim3(256), 0, stream>>>(qb, kb, vb, bias4, xs);
  gemm_out<<<dim3(2048), dim3(256), 0, stream>>>(xs, wout_bf, bout, out);
}

// Round 7
// 266.252 us; speedup vs baseline: 1.2390x; 1.1562x over previous
//
#include <hip/hip_runtime.h>
#include <hip/hip_bf16.h>
#include <stdint.h>

typedef __bf16 bf16;
typedef __attribute__((ext_vector_type(4))) float f32x4;
typedef __attribute__((ext_vector_type(8))) bf16 bf16x8;
typedef __attribute__((ext_vector_type(4))) bf16 bf16x4;

#define AS1 __attribute__((address_space(1)))
#define AS3 __attribute__((address_space(3)))

static __device__ __forceinline__ void gload_lds16(const bf16* g, bf16* l) {
  __builtin_amdgcn_global_load_lds((const AS1 void*)g, (AS3 void*)l, 16, 0, 0);
}

#define BAR __builtin_amdgcn_s_barrier()
#define LGKM0 asm volatile("s_waitcnt lgkmcnt(0)" ::: "memory")
#define VMC(n) asm volatile("s_waitcnt vmcnt(" #n ")" ::: "memory")
#define SCHED0 __builtin_amdgcn_sched_barrier(0)

// ---- 256-thread staging (gemm_out): one 128x64 bf16 tile, 4 chunks/thread ----
#define STAGE_A(gsrc, dst, kt_) do {                                          \
  _Pragma("unroll") for (int s_ = 0; s_ < 4; ++s_) {                          \
    int idx_ = s_ * 256 + tid;                                                \
    int r_ = idx_ >> 3, c_ = idx_ & 7;                                        \
    gload_lds16((gsrc) + (size_t)r_ * 512 + ((kt_) << 6) + ((c_ ^ (r_ & 7)) << 3), \
                (dst) + idx_ * 8);                                            \
  }                                                                           \
} while (0)

// ---- 512-thread staging (qkv_attn): 2 chunks/thread ----
#define STAGE_A2(gsrc, dst, kt_) do {                                         \
  _Pragma("unroll") for (int s_ = 0; s_ < 2; ++s_) {                          \
    int idx_ = s_ * 512 + tid;                                                \
    int r_ = idx_ >> 3, c_ = idx_ & 7;                                        \
    gload_lds16((gsrc) + (size_t)r_ * 512 + ((kt_) << 6) + ((c_ ^ (r_ & 7)) << 3), \
                (dst) + idx_ * 8);                                            \
  }                                                                           \
} while (0)

// B fragments from L2 (K-major layout bt[k/8][col][8]); 4 col-blocks (gemm_out)
#define LOADB(ktq, NCOLX) do {                                                \
  const bf16* bp_ = Bptr + (size_t)(ktq) * ((size_t)(NCOLX) * 64);            \
  _Pragma("unroll") for (int cb_ = 0; cb_ < 4; ++cb_)                         \
  _Pragma("unroll") for (int ks_ = 0; ks_ < 2; ++ks_)                         \
    bfr[cb_][ks_] = *(const bf16x8*)(bp_ + cb_ * 128 + (size_t)ks_ * (NCOLX) * 32); \
} while (0)

// 6 col-blocks (qkv_attn, ncol=1536)
#define LOADB6(ktq) do {                                                      \
  const bf16* bp_ = Bptr + (size_t)(ktq) * 98304;                             \
  _Pragma("unroll") for (int cb_ = 0; cb_ < 6; ++cb_)                         \
  _Pragma("unroll") for (int ks_ = 0; ks_ < 2; ++ks_)                         \
    bfr[cb_][ks_] = *(const bf16x8*)(bp_ + cb_ * 128 + ks_ * 49152);          \
} while (0)

// gemm_out K-loop (round-6, verified): A dbuf in LDS, B in regs from L2.
#define KLOOP_BD(Ag, NCOLX)                                                   \
  f32x4 acc[4][4] = {};                                                       \
  bf16x8 af[4][2], bfr[4][2];                                                 \
  STAGE_A(Ag, SA0, 0);                                                        \
  LOADB(0, NCOLX);                                                            \
  VMC(8); BAR;                                                                \
  STAGE_A(Ag, SA1, 1);                                                        \
  _Pragma("unroll 2")                                                         \
  for (int kt = 0; kt < 8; ++kt) {                                            \
    bf16* Ap = (kt & 1) ? SA1 : SA0;                                          \
    _Pragma("unroll") for (int i_ = 0; i_ < 4; ++i_) {                        \
      int ra_ = wr + i_ * 16 + lr;                                            \
      _Pragma("unroll") for (int ks_ = 0; ks_ < 2; ++ks_)                     \
        af[i_][ks_] = *(const bf16x8*)(Ap + ra_ * 64 + (((ks_ * 4 + lg) ^ (ra_ & 7)) << 3)); \
    }                                                                         \
    LGKM0; SCHED0;                                                            \
    __builtin_amdgcn_s_setprio(1);                                            \
    _Pragma("unroll") for (int i_ = 0; i_ < 4; ++i_)                          \
    _Pragma("unroll") for (int j_ = 0; j_ < 4; ++j_)                          \
    _Pragma("unroll") for (int ks_ = 0; ks_ < 2; ++ks_)                       \
      acc[i_][j_] = __builtin_amdgcn_mfma_f32_16x16x32_bf16(                  \
          af[i_][ks_], bfr[j_][ks_], acc[i_][j_], 0, 0, 0);                   \
    __builtin_amdgcn_s_setprio(0);                                            \
    if (kt < 7) LOADB(kt + 1, NCOLX);                                         \
    if (kt < 7) { VMC(8); }                                                   \
    BAR;                                                                      \
    if (kt < 6) STAGE_A(Ag, Ap, kt + 2);                                      \
  }

// ---------------- prep: roll + reorder + fp32->bf16 ----------------
__global__ __launch_bounds__(256) void prep_x(const float* __restrict__ x,
                                              bf16* __restrict__ xs) {
  int m = blockIdx.x * 8 + (threadIdx.x >> 5);
  int lane = threadIdx.x & 31;
  int b = m >> 12, win = (m >> 6) & 63, t = m & 63;
  int ip = ((win >> 3) << 3) + (t >> 3);
  int jp = ((win & 7) << 3) + (t & 7);
  int io = (ip + 4) & 63, jo = (jp + 4) & 63;
  const float* src = x + ((((size_t)(b << 6) + io) << 6) + jo) * 512;
  bf16* dst = xs + ((size_t)m << 9);
  #pragma unroll
  for (int c0 = 0; c0 < 512; c0 += 128) {
    int c = c0 + lane * 4;
    float4 v = *(const float4*)(src + c);
    bf16x4 o = { (bf16)v.x, (bf16)v.y, (bf16)v.z, (bf16)v.w };
    *(bf16x4*)(dst + c) = o;
  }
}

// Weights -> bf16, K-major-grouped bt[k/8][col][8]. q-scale folded.
// wqkv cols permuted to head-major: col2 = h*96 + part*32 + d
// (so one 96-col strip = {q|k|v} of head h). wout cols unpermuted.
__global__ __launch_bounds__(256) void prep_w(const float* __restrict__ wqkv,
                                              const float* __restrict__ wout,
                                              bf16* __restrict__ wqkv_bt,
                                              bf16* __restrict__ wout_bt) {
  int r = blockIdx.x * 8 + (threadIdx.x >> 5);
  int lane = threadIdx.x & 31;
  const float* src;
  bf16* dstb;
  int ncol, col;
  float sc = 1.0f;
  if (r < 1536) {
    int part = r >> 9, h = (r >> 5) & 15, d = r & 31;
    src = wqkv + (size_t)r * 512; dstb = wqkv_bt; ncol = 1536;
    col = h * 96 + part * 32 + d;
    if (part == 0) sc = 0.17677669529663689f;
  } else {
    src = wout + (size_t)(r - 1536) * 512; dstb = wout_bt; ncol = 512; col = r - 1536;
  }
  #pragma unroll
  for (int kb = lane; kb < 64; kb += 32) {
    float4 v0 = *(const float4*)(src + kb * 8);
    float4 v1 = *(const float4*)(src + kb * 8 + 4);
    bf16x8 o = { (bf16)(v0.x * sc), (bf16)(v0.y * sc), (bf16)(v0.z * sc), (bf16)(v0.w * sc),
                 (bf16)(v1.x * sc), (bf16)(v1.y * sc), (bf16)(v1.z * sc), (bf16)(v1.w * sc) };
    *(bf16x8*)(dstb + ((size_t)kb * ncol + col) * 8) = o;
  }
}

__global__ __launch_bounds__(256) void prep_bias(const float* __restrict__ pos,
                                                 float* __restrict__ bias4) {
  for (int idx = threadIdx.x; idx < 4 * 4096; idx += 256) {
    int ty = idx >> 12, ij = idx & 4095;
    int i = ij >> 6, j = ij & 63;
    int rx = ((j >> 3) - (i >> 3)) + 7;
    int ry = ((j & 7) - (i & 7)) + 7;
    float v = pos[rx * 15 + ry];
    if ((ty & 1) && (((i ^ j) >> 5) & 1)) v = -1e30f;
    if ((ty & 2) && (((i ^ j) >> 2) & 1)) v = -1e30f;
    bias4[idx] = v;
  }
}

// ---------------- fused QKV-GEMM + window attention ----------------
// Block: 128 tokens (2 windows) x 4 heads; 512 thr = 8 waves = 8 (window,head)
// units. Wave accumulates its 64x96 q|k|v slab over K=512 (A from LDS dbuf,
// B from L2), restages it into a PRIVATE 12KB LDS region (q|k row-major,
// v transposed; XOR-swizzled), then does attn fully in-wave.
__global__ __launch_bounds__(512, 1) void qkv_attn(
    const bf16* __restrict__ xs, const bf16* __restrict__ wb2,
    const float* __restrict__ bias4, bf16* __restrict__ ao) {
  __shared__ union { bf16 A[2][8192]; bf16 E[8][6144]; } sm;
  bf16* SA0 = sm.A[0]; bf16* SA1 = sm.A[1];

  const int tid = threadIdx.x, wave = tid >> 6, lane = tid & 63;
  const int ww = wave & 1, wh = wave >> 1;     // window-in-tile, head-in-group
  const int lr = lane & 15, lg = lane >> 4;

  int bid = blockIdx.x;
  bid = (bid & 7) * 256 + (bid >> 3);          // XCD swizzle (2048 = 8*256)
  const int mt = bid >> 2, hg = bid & 3;
  const int h = hg * 4 + wh;

  const bf16* Ag = xs + ((size_t)mt * 128) * 512;
  const bf16* Bptr = wb2 + (((size_t)lg * 1536) + h * 96 + lr) * 8;

  f32x4 acc[4][6] = {};
  bf16x8 af[4][2], bfr[6][2];

  // K-loop: invariant entering kt: Bf(kt)[12] + Ast(kt+1)[2] in flight.
  STAGE_A2(Ag, SA0, 0);
  LOADB6(0);
  VMC(12); BAR;                 // drain Ast(0), publish A(0)
  STAGE_A2(Ag, SA1, 1);
  #pragma unroll 2
  for (int kt = 0; kt < 8; ++kt) {
    bf16* Ap = (kt & 1) ? SA1 : SA0;
    #pragma unroll
    for (int i_ = 0; i_ < 4; ++i_) {
      int ra_ = ww * 64 + i_ * 16 + lr;
      #pragma unroll
      for (int ks_ = 0; ks_ < 2; ++ks_)
        af[i_][ks_] = *(const bf16x8*)(Ap + ra_ * 64 + (((ks_ * 4 + lg) ^ (ra_ & 7)) << 3));
    }
    LGKM0; SCHED0;
    __builtin_amdgcn_s_setprio(1);
    #pragma unroll
    for (int i_ = 0; i_ < 4; ++i_)
      #pragma unroll
      for (int j_ = 0; j_ < 6; ++j_)
        #pragma unroll
        for (int ks_ = 0; ks_ < 2; ++ks_)
          acc[i_][j_] = __builtin_amdgcn_mfma_f32_16x16x32_bf16(
              af[i_][ks_], bfr[j_][ks_], acc[i_][j_], 0, 0, 0);
    __builtin_amdgcn_s_setprio(0);
    if (kt < 7) { LOADB6(kt + 1); VMC(12); }  // drain Ast(kt+1), keep B(kt+1)
    BAR;                                       // publish A(kt+1)
    if (kt < 6) STAGE_A2(Ag, Ap, kt + 2);
  }
  // ---- per-wave epilogue (private LDS region; no cross-wave sync) ----
  bf16* Ew = sm.E[wave];
  // write q|k (cols 0-63 of slab) row-major [64][64] XOR-swizzled,
  // and v (cols 64-95) transposed [32 dims][64 tokens] XOR-swizzled at +4096
  #pragma unroll
  for (int i = 0; i < 4; ++i)
    #pragma unroll
    for (int r = 0; r < 4; ++r) {
      int row = i * 16 + (lg << 2) + r;        // token
      #pragma unroll
      for (int j = 0; j < 4; ++j) {
        int c = j * 16 + lr;
        Ew[row * 64 + (c ^ ((row & 7) << 3))] = (bf16)acc[i][j][r];
      }
      #pragma unroll
      for (int j = 4; j < 6; ++j) {
        int cv = (j - 4) * 16 + lr;            // v dim
        Ew[4096 + cv * 64 + (row ^ ((cv & 7) << 3))] = (bf16)acc[i][j][r];
      }
    }
  LGKM0; SCHED0;
  // read q,k fragments
  bf16x8 qf[4], kf[4];
  #pragma unroll
  for (int i = 0; i < 4; ++i) {
    int ra = i * 16 + lr;
    qf[i] = *(const bf16x8*)(Ew + ra * 64 + (((lg << 3)) ^ ((ra & 7) << 3)));
    kf[i] = *(const bf16x8*)(Ew + ra * 64 + ((32 + (lg << 3)) ^ ((ra & 7) << 3)));
  }
  f32x4 s[4][4] = {};
  #pragma unroll
  for (int i = 0; i < 4; ++i)
    #pragma unroll
    for (int j = 0; j < 4; ++j)
      s[i][j] = __builtin_amdgcn_mfma_f32_16x16x32_bf16(qf[i], kf[j], s[i][j], 0, 0, 0);

  const int gw = mt * 2 + ww;                  // global window id
  const int win = gw & 63;
  const int ty = ((win >= 56) ? 1 : 0) | (((win & 7) == 7) ? 2 : 0);
  const float* bt = bias4 + ty * 4096;
  #pragma unroll
  for (int i = 0; i < 4; ++i)
    #pragma unroll
    for (int r = 0; r < 4; ++r) {
      int row = i * 16 + (lg << 2) + r;
      #pragma unroll
      for (int j = 0; j < 4; ++j)
        s[i][j][r] += bt[row * 64 + j * 16 + lr];
    }
  // wave-parallel softmax; P written into the (dead) q|k region, swizzled
  #pragma unroll
  for (int i = 0; i < 4; ++i)
    #pragma unroll
    for (int r = 0; r < 4; ++r) {
      float mx = fmaxf(fmaxf(s[i][0][r], s[i][1][r]), fmaxf(s[i][2][r], s[i][3][r]));
      mx = fmaxf(mx, __shfl_xor(mx, 1));
      mx = fmaxf(mx, __shfl_xor(mx, 2));
      mx = fmaxf(mx, __shfl_xor(mx, 4));
      mx = fmaxf(mx, __shfl_xor(mx, 8));
      float sum = 0.f;
      #pragma unroll
      for (int j = 0; j < 4; ++j) { s[i][j][r] = __expf(s[i][j][r] - mx); sum += s[i][j][r]; }
      sum += __shfl_xor(sum, 1);
      sum += __shfl_xor(sum, 2);
      sum += __shfl_xor(sum, 4);
      sum += __shfl_xor(sum, 8);
      float inv = 1.0f / sum;
      int row = i * 16 + (lg << 2) + r;
      #pragma unroll
      for (int j = 0; j < 4; ++j) {
        int c = j * 16 + lr;
        Ew[row * 64 + (c ^ ((row & 7) << 3))] = (bf16)(s[i][j][r] * inv);
      }
    }
  LGKM0; SCHED0;
  // PV: out[64x32] = P[64x64] @ V; vT[d][t] is K(token)-contiguous
  f32x4 o[4][2] = {};
  #pragma unroll
  for (int kk = 0; kk < 2; ++kk) {
    bf16x8 vf[2];
    #pragma unroll
    for (int nj = 0; nj < 2; ++nj) {
      int dv = nj * 16 + lr;
      vf[nj] = *(const bf16x8*)(Ew + 4096 + dv * 64 + ((kk * 32 + (lg << 3)) ^ ((dv & 7) << 3)));
    }
    #pragma unroll
    for (int mi = 0; mi < 4; ++mi) {
      int ra = mi * 16 + lr;
      bf16x8 pa = *(const bf16x8*)(Ew + ra * 64 + ((kk * 32 + (lg << 3)) ^ ((ra & 7) << 3)));
      #pragma unroll
      for (int nj = 0; nj < 2; ++nj)
        o[mi][nj] = __builtin_amdgcn_mfma_f32_16x16x32_bf16(pa, vf[nj], o[mi][nj], 0, 0, 0);
    }
  }
  // write ao rows (K-contiguous for out-proj GEMM): row m = mt*128+ww*64+t
  bf16* dst = ao + ((size_t)(mt * 128 + ww * 64)) * 512 + h * 32;
  #pragma unroll
  for (int mi = 0; mi < 4; ++mi)
    #pragma unroll
    for (int r = 0; r < 4; ++r) {
      int t = mi * 16 + (lg << 2) + r;
      #pragma unroll
      for (int nj = 0; nj < 2; ++nj)
        dst[(size_t)t * 512 + nj * 16 + lr] = (bf16)o[mi][nj][r];
    }
}

// ---------------- out-proj GEMM + bias + inverse roll ----------------
__global__ __launch_bounds__(256, 3) void gemm_out(
    const bf16* __restrict__ ao, const bf16* __restrict__ wob,
    const float* __restrict__ bout, float* __restrict__ out) {
  __shared__ bf16 SA[2][8192];
  bf16* SA0 = SA[0]; bf16* SA1 = SA[1];

  const int tid = threadIdx.x, wave = tid >> 6, lane = tid & 63;
  int bid = blockIdx.x;
  bid = (bid & 7) * 256 + (bid >> 3);          // XCD swizzle (2048 = 8*256)
  const int mt = bid >> 2, nt = bid & 3;
  const bf16* Ag = ao + ((size_t)mt * 128) * 512;
  const int wr = (wave >> 1) << 6, wc = (wave & 1) << 6;
  const int lr = lane & 15, lg = lane >> 4;
  const bf16* Bptr = wob + (((size_t)lg * 512) + nt * 128 + wc + lr) * 8;

  KLOOP_BD(Ag, 512)

  float bv[4];
  #pragma unroll
  for (int j = 0; j < 4; ++j) bv[j] = bout[nt * 128 + wc + j * 16 + lr];
  #pragma unroll
  for (int i = 0; i < 4; ++i)
    #pragma unroll
    for (int r = 0; r < 4; ++r) {
      int m = (mt << 7) + wr + i * 16 + (lg << 2) + r;
      int b = m >> 12, win = (m >> 6) & 63, t = m & 63;
      int ip = ((win >> 3) << 3) + (t >> 3);
      int jp = ((win & 7) << 3) + (t & 7);
      int io = (ip + 4) & 63, jo = (jp + 4) & 63;
      float* orow = out + ((((size_t)(b << 6) + io) << 6) + jo) * 512 + nt * 128 + wc;
      #pragma unroll
      for (int j = 0; j < 4; ++j)
        orow[j * 16 + lr] = acc[i][j][r] + bv[j];
    }
}

extern "C" void kernel_launch(void* const* d_in, const int* in_sizes, int n_in,
                              void* d_out, int out_size, void* d_ws, size_t ws_size,
                              hipStream_t stream) {
  const float* x    = (const float*)d_in[0];
  const float* wqkv = (const float*)d_in[1];
  const float* pos  = (const float*)d_in[2];
  const float* wout = (const float*)d_in[3];
  const float* bout = (const float*)d_in[4];
  float* out = (float*)d_out;

  char* ws = (char*)d_ws;
  bf16* xs      = (bf16*)(ws);                 // 64 MB
  bf16* ao      = (bf16*)(ws + 67108864);      // 64 MB
  bf16* wqkv_bt = (bf16*)(ws + 268435456);
  bf16* wout_bt = (bf16*)(ws + 270008320);
  float* bias4  = (float*)(ws + 270532608);

  prep_x<<<dim3(8192), dim3(256), 0, stream>>>(x, xs);
  prep_w<<<dim3(256), dim3(256), 0, stream>>>(wqkv, wout, wqkv_bt, wout_bt);
  prep_bias<<<dim3(1), dim3(256), 0, stream>>>(pos, bias4);
  qkv_attn<<<dim3(2048), dim3(512), 0, stream>>>(xs, wqkv_bt, bias4, ao);
  gemm_out<<<dim3(2048), dim3(256), 0, stream>>>(ao, wout_bt, bout, out);
}